// Round 2
// baseline (231.770 us; speedup 1.0000x reference)
//
#include <hip/hip_runtime.h>

#define SEQ 128
#define BATCH 512
#define IN_DIM 128
#define HID 128

typedef float vf2 __attribute__((ext_vector_type(2)));

__device__ __forceinline__ float rcp_f(float x) { return __builtin_amdgcn_rcpf(x); }
__device__ __forceinline__ float tanh_f(float x) { return 1.0f - 2.0f * rcp_f(__expf(2.0f * x) + 1.0f); }

template <int CTRL>
__device__ __forceinline__ float dpp_add(float s) {
  return s + __int_as_float(__builtin_amdgcn_mov_dpp(__float_as_int(s), CTRL, 0xF, 0xF, true));
}
__device__ __forceinline__ float rdlane(float v, int src) {
  return __int_as_float(__builtin_amdgcn_readlane(__float_as_int(v), src));
}

// LDS-only barrier: does NOT drain vmcnt (X prefetch / out stores stay in flight).
#define BARRIER() asm volatile("s_waitcnt lgkmcnt(0)\n\ts_barrier" ::: "memory")

// Block = 256 = 4 waves, one block per batch element.  Wave g owns gate g.
// In-wave lane roles: r = lane>>3 (wire), c = lane&7 (16-dim chunk of x and h).
// Per step: each wave computes the FULL q_in dot + sincos + its gate's TM chain
// (fused gate GEMM, 2 output dims per lane), gates exchanged via LDS (bar A),
// cell update replicated in every wave, h republished swizzled (bar B).
__global__ __launch_bounds__(256) void qlstm_kernel(
    const float* __restrict__ X, const float* __restrict__ Wq, const float* __restrict__ bq,
    const float* __restrict__ pf, const float* __restrict__ pi_, const float* __restrict__ pg,
    const float* __restrict__ po, const float* __restrict__ Wf, const float* __restrict__ bf,
    const float* __restrict__ Wi, const float* __restrict__ bi, const float* __restrict__ Wg,
    const float* __restrict__ bg, const float* __restrict__ Wo, const float* __restrict__ bo,
    float* __restrict__ out)
{
  __shared__ __align__(16) float gsh[4 * HID];  // [gate][128]
  __shared__ __align__(16) float hsw[HID];      // h, swizzled: granule = chunk + 8*quad

  const int tid  = threadIdx.x;
  const int g    = tid >> 6;
  const int lane = tid & 63;
  const int r    = lane >> 3;
  const int c    = lane & 7;
  const int b    = blockIdx.x;

  const float* gW = (g == 0) ? Wf : (g == 1) ? Wi : (g == 2) ? Wg : Wo;
  const float* gB = (g == 0) ? bf : (g == 1) ? bi : (g == 2) ? bg : bo;
  const float* gP = (g == 0) ? pf : (g == 1) ? pi_ : (g == 2) ? pg : po;

  // ---- one-time register preloads ----
  // q_in dot weights: wire r, x dims 16c..16c+15 and h dims 16c..16c+15
  vf2 wx[8], wh[8];
  {
    const vf2* pxw = (const vf2*)(Wq + r * 256 + 16 * c);
    const vf2* phw = (const vf2*)(Wq + r * 256 + 128 + 16 * c);
#pragma unroll
    for (int j = 0; j < 8; ++j) { wx[j] = pxw[j]; wh[j] = phw[j]; }
  }
  const float bqv = bq[r];

  const float amul = (g == 2) ? 2.0f : 1.0f;   // tanh = 2*sigmoid(2x)-1
  const float oadd = (g == 2) ? -1.0f : 0.0f;
  const float ksc  = -amul;                    // fold -amul into gate weights

  const int d0 = 2 * lane;                     // this lane's 2 output dims
  vf2 wg2[8];
#pragma unroll
  for (int w = 0; w < 8; ++w) {
    wg2[w].x = gW[d0 * 8 + w] * ksc;
    wg2[w].y = gW[(d0 + 1) * 8 + w] * ksc;
  }
  vf2 bias2; bias2.x = gB[d0] * ksc; bias2.y = gB[d0 + 1] * ksc;

  // TM constants for this wave's gate
  vf2 cbsb[8]; float C1[8], S1[8];
#pragma unroll
  for (int w = 0; w < 8; ++w) {
    float th0 = gP[w], th1 = gP[8 + w];
    cbsb[w].x = cosf(th0); cbsb[w].y = sinf(th0);
    C1[w] = cosf(th1); S1[w] = sinf(th1);
  }

  // Swizzled h addresses.  dim d lives at granule (d>>4) + 8*((d&15)>>2),
  // word (d&3).  b64 writes: 2 lanes/granule on disjoint bank halves.
  // b128 reads (per j): 8 granules with distinct index mod 8 -> conflict-free.
  float* hw_w = (float*)((char*)hsw + (16 * r + 128 * (c >> 1) + 8 * (c & 1)));
  const float4* hw_r = (const float4*)((char*)hsw + 16 * c);  // + offsets 0,128,256,384

  float c0r = 0.f, c1r = 0.f, h0v = 0.f, h1v = 0.f;
  if (g == 3) { vf2 z2; z2.x = 0.f; z2.y = 0.f; *(vf2*)hw_w = z2; }
  __syncthreads();

  const float* xp = X + (size_t)b * IN_DIM + 16 * c;
  float* outp = out + (size_t)b * HID + d0;

  float4 xA0, xA1, xA2, xA3, xB0, xB1, xB2, xB3;
  {
    const float4* p4 = (const float4*)xp;
    xA0 = p4[0]; xA1 = p4[1]; xA2 = p4[2]; xA3 = p4[3];
    xB0 = xA0; xB1 = xA1; xB2 = xA2; xB3 = xA3;
  }

#define QSTEP(Xc0, Xc1, Xc2, Xc3, Xn0, Xn1, Xn2, Xn3, T, PREF)                        \
  {                                                                                   \
    if (PREF) {                                                                       \
      const float4* xn_ = (const float4*)(xp + (size_t)((T) + 1) * (BATCH * IN_DIM)); \
      Xn0 = xn_[0]; Xn1 = xn_[1]; Xn2 = xn_[2]; Xn3 = xn_[3];                         \
    }                                                                                 \
    float4 hh0 = hw_r[0], hh1 = hw_r[8], hh2 = hw_r[16], hh3 = hw_r[24];              \
    vf2 aq = wx[0] * (vf2){Xc0.x, Xc0.y} + wx[1] * (vf2){Xc0.z, Xc0.w}                \
           + wx[2] * (vf2){Xc1.x, Xc1.y} + wx[3] * (vf2){Xc1.z, Xc1.w}                \
           + wx[4] * (vf2){Xc2.x, Xc2.y} + wx[5] * (vf2){Xc2.z, Xc2.w}                \
           + wx[6] * (vf2){Xc3.x, Xc3.y} + wx[7] * (vf2){Xc3.z, Xc3.w}                \
           + wh[0] * (vf2){hh0.x, hh0.y} + wh[1] * (vf2){hh0.z, hh0.w}                \
           + wh[2] * (vf2){hh1.x, hh1.y} + wh[3] * (vf2){hh1.z, hh1.w}                \
           + wh[4] * (vf2){hh2.x, hh2.y} + wh[5] * (vf2){hh2.z, hh2.w}                \
           + wh[6] * (vf2){hh3.x, hh3.y} + wh[7] * (vf2){hh3.z, hh3.w};               \
    float s_ = aq.x + aq.y;                                                           \
    s_ = dpp_add<0xB1>(s_); s_ = dpp_add<0x4E>(s_); s_ = dpp_add<0x141>(s_);          \
    float z_ = s_ + bqv;                                                              \
    float sz_, cz_;                                                                   \
    __sincosf(z_, &sz_, &cz_);                                                        \
    float cqs[8], sqs[8];                                                             \
    _Pragma("unroll")                                                                 \
    for (int w = 0; w < 8; ++w) { cqs[w] = rdlane(cz_, 8 * w); sqs[w] = rdlane(sz_, 8 * w); } \
    vf2 acc = bias2;                                                                  \
    float u_, d_, P_, R_;                                                             \
    {                                                                                 \
      vf2 KA0 = cbsb[0] * cqs[0];                                                     \
      u_ = C1[0]; d_ = C1[0] * KA0.x;                                                 \
      P_ = -S1[0] * KA0.y; R_ = -S1[0] * sqs[0];                                      \
    }                                                                                 \
    _Pragma("unroll")                                                                 \
    for (int w = 1; w < 8; ++w) {                                                     \
      vf2 KA = cbsb[w] * cqs[w];                                                      \
      float K_ = KA.x, A2_ = KA.y, B2_ = sqs[w];                                      \
      float Md = fmaf(A2_, P_, d_);                                                   \
      float MP = fmaf(A2_, d_, P_);                                                   \
      float Mu = fmaf(K_, u_, -(B2_ * R_));                                           \
      float MR = fmaf(B2_, u_, K_ * R_);                                              \
      acc += Md * wg2[w - 1];                                                         \
      u_ = C1[w] * Md; d_ = C1[w] * Mu;                                               \
      P_ = -S1[w] * MP; R_ = -S1[w] * MR;                                             \
    }                                                                                 \
    float ev7_ = d_ + P_;                                                             \
    acc += ev7_ * wg2[7];                                                             \
    float e0_ = __expf(acc.x), e1_ = __expf(acc.y);                                   \
    vf2 ok_;                                                                          \
    ok_.x = fmaf(rcp_f(1.0f + e0_), amul, oadd);                                      \
    ok_.y = fmaf(rcp_f(1.0f + e1_), amul, oadd);                                      \
    *(vf2*)(gsh + g * HID + d0) = ok_;                                                \
    BARRIER();                                                                        \
    vf2 fv = *(const vf2*)(gsh + 0 * HID + d0);                                       \
    vf2 iv = *(const vf2*)(gsh + 1 * HID + d0);                                       \
    vf2 gv = *(const vf2*)(gsh + 2 * HID + d0);                                       \
    vf2 ov = *(const vf2*)(gsh + 3 * HID + d0);                                       \
    c0r = fmaf(fv.x, c0r, iv.x * gv.x);                                               \
    c1r = fmaf(fv.y, c1r, iv.y * gv.y);                                               \
    h0v = ov.x * tanh_f(c0r);                                                         \
    h1v = ov.y * tanh_f(c1r);                                                         \
    if (g == 3) { vf2 hw2; hw2.x = h0v; hw2.y = h1v; *(vf2*)hw_w = hw2; }             \
    if (g == 0) { vf2 o2; o2.x = h0v; o2.y = h1v;                                     \
      *(vf2*)(outp + (size_t)(T) * (BATCH * HID)) = o2; }                             \
    BARRIER();                                                                        \
  }

#pragma unroll 1
  for (int tt = 0; tt < SEQ; tt += 2) {
    QSTEP(xA0, xA1, xA2, xA3, xB0, xB1, xB2, xB3, tt, true);
    QSTEP(xB0, xB1, xB2, xB3, xA0, xA1, xA2, xA3, tt + 1, (tt + 2 < SEQ));
  }
#undef QSTEP

  // hx, cx
  if (g == 0) {
    size_t base = (size_t)SEQ * BATCH * HID;
    vf2 hv; hv.x = h0v; hv.y = h1v;
    vf2 cv; cv.x = c0r; cv.y = c1r;
    *(vf2*)(out + base + (size_t)b * HID + d0) = hv;
    *(vf2*)(out + base + (size_t)BATCH * HID + (size_t)b * HID + d0) = cv;
  }
}

extern "C" void kernel_launch(void* const* d_in, const int* in_sizes, int n_in,
                              void* d_out, int out_size, void* d_ws, size_t ws_size,
                              hipStream_t stream) {
  (void)in_sizes; (void)n_in; (void)out_size; (void)d_ws; (void)ws_size;
  const float* X   = (const float*)d_in[0];
  const float* Wq  = (const float*)d_in[1];
  const float* bq  = (const float*)d_in[2];
  const float* pf  = (const float*)d_in[3];
  const float* pi_ = (const float*)d_in[4];
  const float* pg  = (const float*)d_in[5];
  const float* po  = (const float*)d_in[6];
  const float* Wf  = (const float*)d_in[7];
  const float* bf  = (const float*)d_in[8];
  const float* Wi  = (const float*)d_in[9];
  const float* bi  = (const float*)d_in[10];
  const float* Wg  = (const float*)d_in[11];
  const float* bg  = (const float*)d_in[12];
  const float* Wo  = (const float*)d_in[13];
  const float* bo  = (const float*)d_in[14];
  float* out = (float*)d_out;

  qlstm_kernel<<<BATCH, 256, 0, stream>>>(X, Wq, bq, pf, pi_, pg, po,
                                          Wf, bf, Wi, bi, Wg, bg, Wo, bo, out);
}

// Round 3
// 193.080 us; speedup vs baseline: 1.2004x; 1.2004x over previous
//
#include <hip/hip_runtime.h>

#define SEQ 128
#define BATCH 512
#define IN_DIM 128
#define HID 128

typedef float vf2 __attribute__((ext_vector_type(2)));

#define LOG2E 1.4426950408889634f
#define INV2PI 0.15915494309189535f

__device__ __forceinline__ float rcp_f(float x) { return __builtin_amdgcn_rcpf(x); }
// Guaranteed-native transcendentals (single VOP1 each).
__device__ __forceinline__ float exp2_f(float x) { float r; asm("v_exp_f32 %0, %1" : "=v"(r) : "v"(x)); return r; }
__device__ __forceinline__ float sin2pi_f(float x) { float r; asm("v_sin_f32 %0, %1" : "=v"(r) : "v"(x)); return r; }
__device__ __forceinline__ float cos2pi_f(float x) { float r; asm("v_cos_f32 %0, %1" : "=v"(r) : "v"(x)); return r; }
__device__ __forceinline__ float tanh_f(float x) {
  // tanh(x) = 1 - 2/(exp2(x*2log2e)+1)
  return 1.0f - 2.0f * rcp_f(exp2_f(x * 2.885390082f) + 1.0f);
}

template <int CTRL>
__device__ __forceinline__ float dpp_add(float s) {
  return s + __int_as_float(__builtin_amdgcn_mov_dpp(__float_as_int(s), CTRL, 0xF, 0xF, true));
}
__device__ __forceinline__ float rdlane(float v, int src) {
  return __int_as_float(__builtin_amdgcn_readlane(__float_as_int(v), src));
}

// ONE WAVE per batch element (R0 structure), chain-trimmed:
//  - x-contribution computed OFF-CHAIN one step ahead (double-buffered X regs),
//    folded into the same row8 DPP reduce as the h-partial (no prepass kernel).
//  - sincos broadcast via 16x v_readlane -> SGPRs (no qs LDS round trip).
//  - native v_sin/v_cos/v_exp; -amul*log2e folded into gate weights (act = bare exp2).
//  - cell owns dims {2l,2l+1}: gate reads 4xb64, h publish 1xb64; next-step h reads
//    issued right after the h write (in-wave DS ordering) to hide their latency.
__global__ __launch_bounds__(64) void qlstm_kernel(
    const float* __restrict__ X, const float* __restrict__ Wq, const float* __restrict__ bq,
    const float* __restrict__ pf, const float* __restrict__ pi_, const float* __restrict__ pg,
    const float* __restrict__ po, const float* __restrict__ Wf, const float* __restrict__ bf,
    const float* __restrict__ Wi, const float* __restrict__ bi, const float* __restrict__ Wg,
    const float* __restrict__ bg, const float* __restrict__ Wo, const float* __restrict__ bo,
    float* __restrict__ out)
{
  __shared__ __align__(16) float h_sh[HID];
  __shared__ __align__(16) float gsh[4 * HID];   // [gate][128]

  const int lane = threadIdx.x;
  const int r = lane >> 3, c = lane & 7;         // dot roles: wire r, dims 16c..16c+15
  const int g = lane >> 4, p = lane & 15;        // gate roles: gate g, dims 8p..8p+7
  const int b = blockIdx.x;

  const float* gW = (g == 0) ? Wf : (g == 1) ? Wi : (g == 2) ? Wg : Wo;
  const float* gB = (g == 0) ? bf : (g == 1) ? bi : (g == 2) ? bg : bo;
  const float* gP = (g == 0) ? pf : (g == 1) ? pi_ : (g == 2) ? pg : po;

  // ---- one-time register preloads ----
  vf2 wx[8], wh[8];
  {
    const vf2* pxw = (const vf2*)(Wq + r * 256 + 16 * c);
    const vf2* phw = (const vf2*)(Wq + r * 256 + 128 + 16 * c);
#pragma unroll
    for (int j = 0; j < 8; ++j) { wx[j] = pxw[j]; wh[j] = phw[j]; }
  }
  const float bqv = bq[r];

  const float amul = (g == 2) ? 2.0f : 1.0f;     // tanh = 2*sigmoid(2x)-1
  const float oadd = (g == 2) ? -1.0f : 0.0f;
  const float ksc  = -amul * LOG2E;              // fold into weights: act = exp2(acc)

  vf2 wg2[8][4];
#pragma unroll
  for (int w = 0; w < 8; ++w)
#pragma unroll
    for (int j = 0; j < 4; ++j) {
      wg2[w][j].x = gW[(8 * p + 2 * j)     * 8 + w] * ksc;
      wg2[w][j].y = gW[(8 * p + 2 * j + 1) * 8 + w] * ksc;
    }
  vf2 bias2[4];
#pragma unroll
  for (int j = 0; j < 4; ++j) {
    bias2[j].x = gB[8 * p + 2 * j]     * ksc;
    bias2[j].y = gB[8 * p + 2 * j + 1] * ksc;
  }
  vf2 cbsb[8]; float C1[8], S1[8];
#pragma unroll
  for (int w = 0; w < 8; ++w) {
    float th0 = gP[w], th1 = gP[8 + w];
    cbsb[w].x = cosf(th0); cbsb[w].y = sinf(th0);
    C1[w] = cosf(th1); S1[w] = sinf(th1);
  }

  // state
  vf2 c2; c2.x = 0.f; c2.y = 0.f;
  vf2 h2v; h2v.x = 0.f; h2v.y = 0.f;
  float4 hh0 = {0,0,0,0}, hh1 = {0,0,0,0}, hh2 = {0,0,0,0}, hh3 = {0,0,0,0};

  const float* xg = X + (size_t)b * IN_DIM + 16 * c;
  float* outp = out + (size_t)b * HID + 2 * lane;
  const float4* hp4 = (const float4*)(h_sh + 16 * c);

  // X pipeline: P holds X(even), Q holds X(odd).
  float4 xP0, xP1, xP2, xP3, xQ0, xQ1, xQ2, xQ3;
  float xp_cur;
  {
    const float4* x0_ = (const float4*)xg;
    xP0 = x0_[0]; xP1 = x0_[1]; xP2 = x0_[2]; xP3 = x0_[3];
    vf2 ax = wx[0] * (vf2){xP0.x, xP0.y} + wx[1] * (vf2){xP0.z, xP0.w}
           + wx[2] * (vf2){xP1.x, xP1.y} + wx[3] * (vf2){xP1.z, xP1.w}
           + wx[4] * (vf2){xP2.x, xP2.y} + wx[5] * (vf2){xP2.z, xP2.w}
           + wx[6] * (vf2){xP3.x, xP3.y} + wx[7] * (vf2){xP3.z, xP3.w};
    xp_cur = ax.x + ax.y;
    const float4* x1_ = (const float4*)(xg + (size_t)(BATCH * IN_DIM));
    xQ0 = x1_[0]; xQ1 = x1_[1]; xQ2 = x1_[2]; xQ3 = x1_[3];
  }

#define QSTEP(U0, U1, U2, U3, L0, L1, L2, L3, T)                                      \
  {                                                                                   \
    /* ---- chain: q_in dot (h part + precomputed x partial) ---- */                  \
    vf2 aq = (vf2){xp_cur, 0.0f}                                                      \
           + wh[0] * (vf2){hh0.x, hh0.y} + wh[1] * (vf2){hh0.z, hh0.w}                \
           + wh[2] * (vf2){hh1.x, hh1.y} + wh[3] * (vf2){hh1.z, hh1.w}                \
           + wh[4] * (vf2){hh2.x, hh2.y} + wh[5] * (vf2){hh2.z, hh2.w}                \
           + wh[6] * (vf2){hh3.x, hh3.y} + wh[7] * (vf2){hh3.z, hh3.w};               \
    float s_ = aq.x + aq.y;                                                           \
    s_ = dpp_add<0xB1>(s_); s_ = dpp_add<0x4E>(s_); s_ = dpp_add<0x141>(s_);          \
    float z_ = s_ + bqv;                                                              \
    float m_ = z_ * INV2PI;                                                           \
    float sz_ = sin2pi_f(m_), cz_ = cos2pi_f(m_);                                     \
    float cqs[8], sqs[8];                                                             \
    _Pragma("unroll")                                                                 \
    for (int w = 0; w < 8; ++w) { cqs[w] = rdlane(cz_, 8 * w); sqs[w] = rdlane(sz_, 8 * w); } \
    /* ---- TM chain + fused gate GEMM ---- */                                        \
    vf2 acc0 = bias2[0], acc1 = bias2[1], acc2 = bias2[2], acc3 = bias2[3];           \
    float u_, d_, P_, R_;                                                             \
    {                                                                                 \
      vf2 KA0 = cbsb[0] * cqs[0];                                                     \
      u_ = C1[0]; d_ = C1[0] * KA0.x;                                                 \
      P_ = -S1[0] * KA0.y; R_ = -S1[0] * sqs[0];                                      \
    }                                                                                 \
    _Pragma("unroll")                                                                 \
    for (int w = 1; w < 8; ++w) {                                                     \
      vf2 KA = cbsb[w] * cqs[w];                                                      \
      float K_ = KA.x, A2_ = KA.y, B2_ = sqs[w];                                      \
      float Md = fmaf(A2_, P_, d_);                                                   \
      float MP = fmaf(A2_, d_, P_);                                                   \
      float Mu = fmaf(K_, u_, -(B2_ * R_));                                           \
      float MR = fmaf(B2_, u_, K_ * R_);                                              \
      acc0 += Md * wg2[w - 1][0]; acc1 += Md * wg2[w - 1][1];                         \
      acc2 += Md * wg2[w - 1][2]; acc3 += Md * wg2[w - 1][3];                         \
      u_ = C1[w] * Md; d_ = C1[w] * Mu;                                               \
      P_ = -S1[w] * MP; R_ = -S1[w] * MR;                                             \
    }                                                                                 \
    float ev7_ = d_ + P_;                                                             \
    acc0 += ev7_ * wg2[7][0]; acc1 += ev7_ * wg2[7][1];                               \
    acc2 += ev7_ * wg2[7][2]; acc3 += ev7_ * wg2[7][3];                               \
    /* ---- activation: bare exp2 (scale folded into weights) ---- */                 \
    float av_[8] = {acc0.x, acc0.y, acc1.x, acc1.y, acc2.x, acc2.y, acc3.x, acc3.y};  \
    float o8[8];                                                                      \
    _Pragma("unroll")                                                                 \
    for (int k = 0; k < 8; ++k) {                                                     \
      float e_ = exp2_f(av_[k]);                                                      \
      o8[k] = fmaf(rcp_f(1.0f + e_), amul, oadd);                                     \
    }                                                                                 \
    {                                                                                 \
      float4* gp4 = (float4*)(gsh + g * HID + 8 * p);                                 \
      float4 w0; w0.x = o8[0]; w0.y = o8[1]; w0.z = o8[2]; w0.w = o8[3];              \
      float4 w1; w1.x = o8[4]; w1.y = o8[5]; w1.z = o8[6]; w1.w = o8[7];              \
      gp4[0] = w0; gp4[1] = w1;                                                       \
    }                                                                                 \
    /* ---- off-chain: next x-partial + X prefetch (t+2) ---- */                      \
    {                                                                                 \
      vf2 axn = wx[0] * (vf2){U0.x, U0.y} + wx[1] * (vf2){U0.z, U0.w}                 \
              + wx[2] * (vf2){U1.x, U1.y} + wx[3] * (vf2){U1.z, U1.w}                 \
              + wx[4] * (vf2){U2.x, U2.y} + wx[5] * (vf2){U2.z, U2.w}                 \
              + wx[6] * (vf2){U3.x, U3.y} + wx[7] * (vf2){U3.z, U3.w};                \
      xp_cur = axn.x + axn.y;                                                         \
      int tl_ = ((T) + 2 < SEQ) ? (T) + 2 : (SEQ - 1);                                \
      const float4* xn_ = (const float4*)(xg + (size_t)tl_ * (BATCH * IN_DIM));       \
      L0 = xn_[0]; L1 = xn_[1]; L2 = xn_[2]; L3 = xn_[3];                             \
    }                                                                                 \
    /* ---- cell update (dims 2*lane, 2*lane+1) ---- */                               \
    vf2 fv = *(const vf2*)(gsh + 0 * HID + 2 * lane);                                 \
    vf2 iv = *(const vf2*)(gsh + 1 * HID + 2 * lane);                                 \
    vf2 gv = *(const vf2*)(gsh + 2 * HID + 2 * lane);                                 \
    vf2 ov = *(const vf2*)(gsh + 3 * HID + 2 * lane);                                 \
    c2 = fv * c2 + iv * gv;                                                           \
    h2v.x = ov.x * tanh_f(c2.x);                                                      \
    h2v.y = ov.y * tanh_f(c2.y);                                                      \
    *(vf2*)(h_sh + 2 * lane) = h2v;                                                   \
    /* issue next-step h reads immediately (in-wave DS ordering) */                   \
    hh0 = hp4[0]; hh1 = hp4[1]; hh2 = hp4[2]; hh3 = hp4[3];                           \
    *(vf2*)(outp + (size_t)(T) * (BATCH * HID)) = h2v;                                \
  }

#pragma unroll 1
  for (int tt = 0; tt < SEQ; tt += 2) {
    QSTEP(xQ0, xQ1, xQ2, xQ3, xP0, xP1, xP2, xP3, tt);
    QSTEP(xP0, xP1, xP2, xP3, xQ0, xQ1, xQ2, xQ3, tt + 1);
  }
#undef QSTEP

  // hx, cx
  {
    size_t base = (size_t)SEQ * BATCH * HID;
    *(vf2*)(out + base + (size_t)b * HID + 2 * lane) = h2v;
    *(vf2*)(out + base + (size_t)BATCH * HID + (size_t)b * HID + 2 * lane) = c2;
  }
}

extern "C" void kernel_launch(void* const* d_in, const int* in_sizes, int n_in,
                              void* d_out, int out_size, void* d_ws, size_t ws_size,
                              hipStream_t stream) {
  (void)in_sizes; (void)n_in; (void)out_size; (void)d_ws; (void)ws_size;
  const float* X   = (const float*)d_in[0];
  const float* Wq  = (const float*)d_in[1];
  const float* bq  = (const float*)d_in[2];
  const float* pf  = (const float*)d_in[3];
  const float* pi_ = (const float*)d_in[4];
  const float* pg  = (const float*)d_in[5];
  const float* po  = (const float*)d_in[6];
  const float* Wf  = (const float*)d_in[7];
  const float* bf  = (const float*)d_in[8];
  const float* Wi  = (const float*)d_in[9];
  const float* bi  = (const float*)d_in[10];
  const float* Wg  = (const float*)d_in[11];
  const float* bg  = (const float*)d_in[12];
  const float* Wo  = (const float*)d_in[13];
  const float* bo  = (const float*)d_in[14];
  float* out = (float*)d_out;

  qlstm_kernel<<<BATCH, 64, 0, stream>>>(X, Wq, bq, pf, pi_, pg, po,
                                         Wf, bf, Wi, bi, Wg, bg, Wo, bo, out);
}